// Round 5
// baseline (647.115 us; speedup 1.0000x reference)
//
#include <hip/hip_runtime.h>
#include <hip/hip_cooperative_groups.h>

#define BB   64
#define CC   64
#define NSP  12544     // 112*112
#define NSP4 3136      // NSP/4 (= 49*64)
#define BC   (BB*CC)   // 4096
#define KCL  8
#define NBLK 1024      // 4 blocks/CU -> cooperative co-residency
#define SPB  4         // slices per block == waves per block
#define NFULL 12       // fallback kernels: unrolled loads per thread
#define TAILBASE 3072

typedef float f32x4 __attribute__((ext_vector_type(4)));

// ---------------- Fused cooperative kernel v2 (hardened launch) ----------------
// Block j owns channel c = j&63, samples b = 4*(j>>6)..+3, ONE SLICE PER WAVE.
// Phase 1: per-wave reduction, shuffle-only (no __syncthreads), 8-deep
//          register load chunks (49 = 6*8 + 1 loads/lane).
// grid.sync(): single device-wide barrier.
// Phase 2: per-block redundant cluster stats for channel c (round-1-verified
//          numerics).
// Phase 3: per-wave apply, 8-deep chunks, NT stores; x re-read is L3-hot
//          (round-1 FETCH=196MiB proved full absorption).
__global__ __launch_bounds__(256, 4) void fused_kernel(
    const f32x4* __restrict__ x, const float* __restrict__ cluster_map,
    const float* __restrict__ lmda, f32x4* __restrict__ out,
    float* __restrict__ s1g, float* __restrict__ s2g)
{
    const int j     = blockIdx.x;
    const int t     = threadIdx.x;
    const int wid   = t >> 6;
    const int lane  = t & 63;
    const int c     = j & 63;
    const int bbase = (j >> 6) * SPB;
    const int b     = bbase + wid;

    // ---- Phase 1: my wave's slice ----
    {
        const f32x4* p = x + (size_t)(b * CC + c) * NSP4;
        float a1 = 0.0f, a2 = 0.0f;
        int i = lane;
#pragma unroll 1
        for (int ch = 0; ch < 6; ++ch) {
            f32x4 v[8];
#pragma unroll
            for (int q = 0; q < 8; ++q) v[q] = p[i + q * 64];
#pragma unroll
            for (int q = 0; q < 8; ++q) {
                a1 += v[q].x + v[q].y + v[q].z + v[q].w;
                a2 += v[q].x * v[q].x + v[q].y * v[q].y
                    + v[q].z * v[q].z + v[q].w * v[q].w;
            }
            i += 512;
        }
        {   // 49th load: i = lane + 3072 < 3136
            f32x4 v = p[i];
            a1 += v.x + v.y + v.z + v.w;
            a2 += v.x * v.x + v.y * v.y + v.z * v.z + v.w * v.w;
        }
        for (int off = 32; off > 0; off >>= 1) {
            a1 += __shfl_down(a1, off, 64);
            a2 += __shfl_down(a2, off, 64);
        }
        if (lane == 0) {
            s1g[b * CC + c] = a1;
            s2g[b * CC + c] = a2;
        }
    }

    __threadfence();
    cooperative_groups::this_grid().sync();

    // ---- Phase 2: stats for channel c (per-block redundant, tiny) ----
    __shared__ int   cid[BB];
    __shared__ float s1c[BB], s2c[BB];
    __shared__ float Af[SPB], Bf[SPB];

    if (t < BB) {
        const float* cmp = cluster_map + t * KCL;
        float best = cmp[0];
        int   bi   = 0;
        for (int k = 1; k < KCL; ++k) {
            float q = cmp[k];
            if (q > best) { best = q; bi = k; }
        }
        cid[t] = bi;
        s1c[t] = s1g[t * CC + c];
        s2c[t] = s2g[t * CC + c];
    }
    __syncthreads();

    if (t < SPB) {
        const int bb = bbase + t;
        const int k  = cid[bb];
        double cs1 = 0.0, cs2 = 0.0;
        int cnt = 0;
        for (int b2 = 0; b2 < BB; ++b2) {
            if (cid[b2] == k) { cs1 += (double)s1c[b2]; cs2 += (double)s2c[b2]; ++cnt; }
        }
        double nk = fmax((double)cnt * (double)NSP, 1.0);
        double cm = cs1 / nk;
        double cv = (cs2 - nk * cm * cm) / fmax(nk - 1.0, 1.0);
        float  cmu  = (float)cm;
        float  cstd = sqrtf((float)cv + 1e-6f);

        float sm   = s1c[bb] * (1.0f / NSP);
        float sv   = (s2c[bb] - (float)NSP * sm * sm) * (1.0f / (NSP - 1));
        float sstd = sqrtf(sv + 1e-6f);

        float l       = lmda[bb];
        float mu_mix  = sm   * l + cmu  * (1.0f - l);
        float std_mix = sstd * l + cstd * (1.0f - l);
        float a       = std_mix / sstd;
        Af[t] = a;
        Bf[t] = mu_mix - sm * a;
    }
    __syncthreads();

    // ---- Phase 3: my wave's slice, apply + NT store ----
    {
        const float a  = Af[wid];
        const float bi = Bf[wid];
        const size_t base = (size_t)(b * CC + c) * NSP4;
        int i = lane;
#pragma unroll 1
        for (int ch = 0; ch < 6; ++ch) {
            f32x4 v[8];
#pragma unroll
            for (int q = 0; q < 8; ++q) v[q] = x[base + i + q * 64];
#pragma unroll
            for (int q = 0; q < 8; ++q) {
                f32x4 o;
                o.x = fmaf(v[q].x, a, bi);
                o.y = fmaf(v[q].y, a, bi);
                o.z = fmaf(v[q].z, a, bi);
                o.w = fmaf(v[q].w, a, bi);
                __builtin_nontemporal_store(o, &out[base + i + q * 64]);
            }
            i += 512;
        }
        {
            f32x4 v = x[base + i];
            f32x4 o;
            o.x = fmaf(v.x, a, bi);
            o.y = fmaf(v.y, a, bi);
            o.z = fmaf(v.z, a, bi);
            o.w = fmaf(v.w, a, bi);
            __builtin_nontemporal_store(o, &out[base + i]);
        }
    }
}

// ---------------- Fallback: verified round-2 two-kernel path ----------------
__global__ __launch_bounds__(256) void reduce_kernel(
    const f32x4* __restrict__ x, float* __restrict__ s1, float* __restrict__ s2)
{
    const int bc = blockIdx.x;
    const int t  = threadIdx.x;
    const f32x4* p = x + (size_t)bc * NSP4;

    f32x4 v[NFULL];
#pragma unroll
    for (int j = 0; j < NFULL; ++j) v[j] = p[t + j * 256];
    f32x4 vt;
    const bool tail = (t < 64);
    if (tail) vt = p[TAILBASE + t];

    float a1 = 0.0f, a2 = 0.0f;
#pragma unroll
    for (int j = 0; j < NFULL; ++j) {
        a1 += v[j].x + v[j].y + v[j].z + v[j].w;
        a2 += v[j].x * v[j].x + v[j].y * v[j].y + v[j].z * v[j].z + v[j].w * v[j].w;
    }
    if (tail) {
        a1 += vt.x + vt.y + vt.z + vt.w;
        a2 += vt.x * vt.x + vt.y * vt.y + vt.z * vt.z + vt.w * vt.w;
    }
    for (int off = 32; off > 0; off >>= 1) {
        a1 += __shfl_down(a1, off, 64);
        a2 += __shfl_down(a2, off, 64);
    }
    __shared__ float w1[4], w2[4];
    const int wid = t >> 6;
    if ((t & 63) == 0) { w1[wid] = a1; w2[wid] = a2; }
    __syncthreads();
    if (t == 0) {
        s1[bc] = (w1[0] + w1[1]) + (w1[2] + w1[3]);
        s2[bc] = (w2[0] + w2[1]) + (w2[2] + w2[3]);
    }
}

__global__ __launch_bounds__(256) void apply_kernel(
    const f32x4* __restrict__ x,
    const float* __restrict__ s1, const float* __restrict__ s2,
    const float* __restrict__ cluster_map, const float* __restrict__ lmda,
    f32x4* __restrict__ out)
{
    const int bc = blockIdx.x;
    const int b  = bc >> 6;
    const int c  = bc & 63;
    const int t  = threadIdx.x;
    const size_t base = (size_t)bc * NSP4;

    f32x4 v[NFULL];
#pragma unroll
    for (int j = 0; j < NFULL; ++j) v[j] = x[base + t + j * 256];
    f32x4 vt;
    const bool tail = (t < 64);
    if (tail) vt = x[base + TAILBASE + t];

    __shared__ int   cid[BB];
    __shared__ float s1c[BB], s2c[BB];
    __shared__ float sA, sBias;

    if (t < BB) {
        const float* cmp = cluster_map + t * KCL;
        float best = cmp[0];
        int   bi   = 0;
        for (int k = 1; k < KCL; ++k) {
            float q = cmp[k];
            if (q > best) { best = q; bi = k; }
        }
        cid[t] = bi;
        s1c[t] = s1[t * CC + c];
        s2c[t] = s2[t * CC + c];
    }
    __syncthreads();

    if (t == 0) {
        const int k = cid[b];
        double cs1 = 0.0, cs2 = 0.0;
        int cnt = 0;
        for (int b2 = 0; b2 < BB; ++b2) {
            if (cid[b2] == k) { cs1 += (double)s1c[b2]; cs2 += (double)s2c[b2]; ++cnt; }
        }
        double nk = fmax((double)cnt * (double)NSP, 1.0);
        double cm = cs1 / nk;
        double cv = (cs2 - nk * cm * cm) / fmax(nk - 1.0, 1.0);
        float  cmu  = (float)cm;
        float  cstd = sqrtf((float)cv + 1e-6f);

        float sm   = s1c[b] * (1.0f / NSP);
        float sv   = (s2c[b] - (float)NSP * sm * sm) * (1.0f / (NSP - 1));
        float sstd = sqrtf(sv + 1e-6f);

        float l       = lmda[b];
        float mu_mix  = sm   * l + cmu  * (1.0f - l);
        float std_mix = sstd * l + cstd * (1.0f - l);
        float a       = std_mix / sstd;
        sA    = a;
        sBias = mu_mix - sm * a;
    }
    __syncthreads();

    const float a  = sA;
    const float bi = sBias;

#pragma unroll
    for (int j = 0; j < NFULL; ++j) {
        f32x4 o;
        o.x = fmaf(v[j].x, a, bi);
        o.y = fmaf(v[j].y, a, bi);
        o.z = fmaf(v[j].z, a, bi);
        o.w = fmaf(v[j].w, a, bi);
        __builtin_nontemporal_store(o, &out[base + t + j * 256]);
    }
    if (tail) {
        f32x4 o;
        o.x = fmaf(vt.x, a, bi);
        o.y = fmaf(vt.y, a, bi);
        o.z = fmaf(vt.z, a, bi);
        o.w = fmaf(vt.w, a, bi);
        __builtin_nontemporal_store(o, &out[base + TAILBASE + t]);
    }
}

extern "C" void kernel_launch(void* const* d_in, const int* in_sizes, int n_in,
                              void* d_out, int out_size, void* d_ws, size_t ws_size,
                              hipStream_t stream)
{
    const f32x4* x4 = (const f32x4*)d_in[0];   // [64,64,112,112]
    const float* cm = (const float*)d_in[1];   // [1,64,8]
    const float* lm = (const float*)d_in[2];   // [64,1,1,1]
    f32x4* out4 = (f32x4*)d_out;

    float* s1 = (float*)d_ws;                  // 4096 floats
    float* s2 = s1 + BC;                       // 4096 floats

    // One-time host-side capability check (query-only: capture-safe).
    // Do NOT trust the cooperative runtime's own validation — verify that
    // 1024 blocks of fused_kernel are genuinely co-resident before using
    // grid.sync(); otherwise take the verified two-kernel path.
    static int coop_ok = -1;
    if (coop_ok < 0) {
        int dev = 0;
        (void)hipGetDevice(&dev);
        int supp = 0;
        (void)hipDeviceGetAttribute(&supp, hipDeviceAttributeCooperativeLaunch, dev);
        int ncu = 0;
        (void)hipDeviceGetAttribute(&ncu, hipDeviceAttributeMultiprocessorCount, dev);
        int maxblk = 0;
        hipError_t oe = hipOccupancyMaxActiveBlocksPerMultiprocessor(
            &maxblk, fused_kernel, 256, 0);
        coop_ok = (supp && oe == hipSuccess && ncu > 0 &&
                   (long)maxblk * (long)ncu >= (long)NBLK) ? 1 : 0;
    }

    hipError_t err = hipErrorUnknown;
    if (coop_ok == 1) {
        void* args[] = { (void*)&x4, (void*)&cm, (void*)&lm,
                         (void*)&out4, (void*)&s1, (void*)&s2 };
        err = hipLaunchCooperativeKernel(
            (const void*)fused_kernel, dim3(NBLK), dim3(256), args, 0, stream);
    }

    if (err != hipSuccess) {
        reduce_kernel<<<BC, 256, 0, stream>>>(x4, s1, s2);
        apply_kernel<<<BC, 256, 0, stream>>>(x4, s1, s2, cm, lm, out4);
    }
}